// Round 28
// baseline (123.849 us; speedup 1.0000x reference)
//
#include <hip/hip_runtime.h>
#include <math.h>

// Problem constants
static constexpr int kB = 2;
static constexpr int kS = 2048;
static constexpr int kE = 1024;
static constexpr int kH = 16;
static constexpr int kD = 64;
static constexpr int kTRIL = 2080; // 64*65/2

typedef __attribute__((ext_vector_type(8))) _Float16 f16x8;
typedef __attribute__((ext_vector_type(4))) _Float16 f16x4;
typedef __attribute__((ext_vector_type(2))) __fp16 fp16x2;
typedef __attribute__((ext_vector_type(4))) float f32x4;
typedef __attribute__((ext_vector_type(16))) float f32x16;
typedef __attribute__((ext_vector_type(4))) unsigned int u32x4;
typedef __attribute__((ext_vector_type(2))) unsigned int u32x2;

// Split f32 into f16 hi (RNE) + f16 lo (residual).
__device__ __forceinline__ void split_f16(float f, _Float16& hi, _Float16& lo) {
    hi = (_Float16)f;
    lo = (_Float16)(f - (float)hi);
}

// Async global->LDS 16B copy. LDS dest is wave-uniform (HW adds lane*16).
__device__ __forceinline__ void gload_lds16(const void* g, void* l) {
    __builtin_amdgcn_global_load_lds(
        (const __attribute__((address_space(1))) unsigned int*)g,
        (__attribute__((address_space(3))) unsigned int*)l, 16, 0, 0);
}

// Packed f32x2 -> f16x2 (v_cvt_pkrtz_f16_f32, single VALU op).
__device__ __forceinline__ unsigned pack_f16(float a, float b) {
    fp16x2 p = __builtin_amdgcn_cvt_pkrtz(a, b);
    return __builtin_bit_cast(unsigned, p);
}

// x[lane^32] via v_permlane32_swap (VALU pipe, modeled builtin).
__device__ __forceinline__ unsigned partner32(unsigned x, int hi) {
    u32x2 r = __builtin_amdgcn_permlane32_swap(x, x, false, false);
    return hi ? r[0] : r[1];
}
__device__ __forceinline__ float partner32_f(float x, int hi) {
    return __builtin_bit_cast(float, partner32(__builtin_bit_cast(unsigned, x), hi));
}

__device__ __forceinline__ float max3f(float a, float b, float c) {
    return fmaxf(fmaxf(a, b), c);   // clang fuses to v_max3_f32
}

// ---------------------------------------------------------------------------
// Fused setup:
//   blocks [0,1024)      : cast Wv -> f16
//   blocks [1024,2048)   : cast Wo -> f16
//   blocks [2048,6144)   : cast x -> f16
//   blocks [6144,6160)   : build Wqk[h] = L_h @ L_h^T, split f16 hi/lo
// ---------------------------------------------------------------------------
__global__ __launch_bounds__(256) void setup_kernel(
    const float* __restrict__ Wv, const float* __restrict__ Wo,
    const float* __restrict__ x, const float* __restrict__ params,
    _Float16* __restrict__ wvf, _Float16* __restrict__ wof,
    _Float16* __restrict__ xf,
    _Float16* __restrict__ wqkh, _Float16* __restrict__ wqkl)
{
    const int bid = blockIdx.x;
    if (bid < 2048) {
        const int half = bid >> 10;
        const int i = (bid & 1023) * 256 + threadIdx.x;
        const float* src = half ? Wo : Wv;
        _Float16* dst = half ? wof : wvf;
        const float4 v = ((const float4*)src)[i];
        f16x4 o = {(_Float16)v.x, (_Float16)v.y, (_Float16)v.z, (_Float16)v.w};
        ((f16x4*)dst)[i] = o;
        return;
    }
    if (bid < 6144) {
        const int i = (bid - 2048) * 256 + threadIdx.x;
        const float4 v = ((const float4*)x)[i];
        f16x4 o = {(_Float16)v.x, (_Float16)v.y, (_Float16)v.z, (_Float16)v.w};
        ((f16x4*)xf)[i] = o;
        return;
    }
    // build_wqk for head h (symmetric), emit f16 hi/lo split
    __shared__ float p[kTRIL];
    const int h = bid - 6144;
    for (int i = threadIdx.x; i < kTRIL; i += 256) p[i] = params[h * kTRIL + i];
    __syncthreads();
    for (int idx = threadIdx.x; idx < kD * kD; idx += 256) {
        const int i = idx >> 6;
        const int j = idx & 63;
        const int m = i < j ? i : j;
        const float* pi = p + (i * (i + 1)) / 2;
        const float* pj = p + (j * (j + 1)) / 2;
        float s = 0.f;
        for (int k = 0; k <= m; ++k) s += pi[k] * pj[k];
        _Float16 a, b;
        split_f16(s, a, b);
        wqkh[h * kD * kD + idx] = a;
        wqkl[h * kD * kD + idx] = b;
    }
}

// ---------------------------------------------------------------------------
// Fused middle stage:
//   blocks [0,512)     : V-projection GEMM, 128x64 tile (2 blocks/CU, 48KB
//                        LDS -> 3 resident) -> VtG f16 [b,h,d,s]
//   blocks [512,1024)  : Q-projection via MFMA, per (b,h,128-token group).
// ---------------------------------------------------------------------------
__global__ __launch_bounds__(256) void mid_kernel(
    const _Float16* __restrict__ xf, const _Float16* __restrict__ wvf,
    const float* __restrict__ bv, _Float16* __restrict__ VtG,
    const _Float16* __restrict__ wqkh, const _Float16* __restrict__ wqkl,
    _Float16* __restrict__ Qhf, _Float16* __restrict__ Qlf)
{
    __shared__ char arena[49152];
    const int tid = threadIdx.x;
    const int w = tid >> 6, l = tid & 63;
    const int srow = 8 * w + (l >> 3);
    const int cpos = l & 7;

    if (blockIdx.x < 512) {
        // ------- V GEMM: BM=128, BN=64, BK=64, dbuf -------
        _Float16 (*Ab)[128 * 64] = (_Float16 (*)[128 * 64])arena;          // 2x16KB
        _Float16 (*Bb)[64 * 64]  = (_Float16 (*)[64 * 64])(arena + 32768); // 2x8KB
        const int K_ = kE;
        const int g = l >> 4, lm = l & 15;
        const int wm = w >> 1, wn = w & 1;
        const int bm = (blockIdx.x >> 4) * 128, bn = (blockIdx.x & 15) * 64;

        f32x4 acc[4][2];
#pragma unroll
        for (int i = 0; i < 4; ++i)
#pragma unroll
            for (int j = 0; j < 2; ++j) acc[i][j] = (f32x4){0.f, 0.f, 0.f, 0.f};

        auto stage = [&](int buf, int k0) {
#pragma unroll
            for (int j = 0; j < 4; ++j) {
                const int r = 32 * j + srow;
                const int c = cpos ^ (r & 7);
                gload_lds16(xf + (size_t)(bm + r) * K_ + k0 + c * 8, &Ab[buf][j * 2048 + w * 512]);
            }
#pragma unroll
            for (int j = 0; j < 2; ++j) {
                const int r = 32 * j + srow;
                const int c = cpos ^ (r & 7);
                gload_lds16(wvf + (size_t)(bn + r) * K_ + k0 + c * 8, &Bb[buf][j * 2048 + w * 512]);
            }
        };

        stage(0, 0);
        __syncthreads();
        int cur = 0;
        const int NT = K_ / 64;
        for (int t = 0; t < NT; ++t) {
            if (t + 1 < NT) stage(cur ^ 1, 64 * (t + 1));
            f16x8 a[4][2], bf[2][2];
#pragma unroll
            for (int i = 0; i < 4; ++i) {
                const int rA = wm * 64 + i * 16 + lm;
#pragma unroll
                for (int ks = 0; ks < 2; ++ks)
                    a[i][ks] = *(const f16x8*)&Ab[cur][rA * 64 + (((4 * ks + g) ^ (rA & 7)) * 8)];
            }
#pragma unroll
            for (int i = 0; i < 2; ++i) {
                const int rB = wn * 32 + i * 16 + lm;
#pragma unroll
                for (int ks = 0; ks < 2; ++ks)
                    bf[i][ks] = *(const f16x8*)&Bb[cur][rB * 64 + (((4 * ks + g) ^ (rB & 7)) * 8)];
            }
            __builtin_amdgcn_s_setprio(1);
#pragma unroll
            for (int ks = 0; ks < 2; ++ks)
#pragma unroll
                for (int mi = 0; mi < 4; ++mi)
#pragma unroll
                    for (int ni = 0; ni < 2; ++ni)
                        acc[mi][ni] = __builtin_amdgcn_mfma_f32_16x16x32_f16(
                            a[mi][ks], bf[ni][ks], acc[mi][ni], 0, 0, 0);
            __builtin_amdgcn_s_setprio(0);
            __syncthreads();
            cur ^= 1;
        }

#pragma unroll
        for (int ni = 0; ni < 2; ++ni) {
            const int col = bn + wn * 32 + ni * 16 + lm;
            const float bb = bv[col];
            const int hh = col >> 6, dd = col & 63;
#pragma unroll
            for (int mi = 0; mi < 4; ++mi) {
                const int tok = bm + wm * 64 + mi * 16 + g * 4;
                const int b = tok >> 11, s0 = tok & 2047;
                f16x4 pk;
#pragma unroll
                for (int r = 0; r < 4; ++r) pk[r] = (_Float16)(acc[mi][ni][r] + bb);
                *(f16x4*)(VtG + ((size_t)(b * kH + hh) * kD + dd) * kS + s0) = pk;
            }
        }
    } else {
        // ---------------- Q projection via MFMA ----------------
        _Float16* Wh = (_Float16*)arena;                 // [64][64] swizzled
        _Float16* Wl = (_Float16*)(arena + 8192);
        const int wk = blockIdx.x - 512;
        const int b = wk >> 8;
        const int h = (wk >> 4) & 15;
        const int tg = wk & 15;
        const int hi = l >> 5;
        const int lq = l & 31;

#pragma unroll
        for (int j = 0; j < 2; ++j) {
            const int r = 32 * j + srow;
            const int c = cpos ^ (r & 7);
            gload_lds16(wqkh + (size_t)(h * kD + r) * kD + c * 8, &Wh[j * 2048 + w * 512]);
            gload_lds16(wqkl + (size_t)(h * kD + r) * kD + c * 8, &Wl[j * 2048 + w * 512]);
        }

        const int tok = tg * 128 + 32 * w + lq;
        f16x8 xq[4];
        {
            const size_t xoff = ((size_t)(b * kS + tok)) * kE + h * kD + 8 * hi;
#pragma unroll
            for (int ks = 0; ks < 4; ++ks)
                xq[ks] = *(const f16x8*)(xf + xoff + 16 * ks);
        }
        f32x16 acc[2];
#pragma unroll
        for (int r = 0; r < 16; ++r) { acc[0][r] = 0.f; acc[1][r] = 0.f; }
        __syncthreads();

#pragma unroll
        for (int et = 0; et < 2; ++et) {
            const int r = 32 * et + lq;
            const int rb = r * 64;
            const int rsw = r & 7;
#pragma unroll
            for (int ks = 0; ks < 4; ++ks) {
                const int cd = 2 * ks + hi;
                f16x8 wh = *(const f16x8*)&Wh[rb + ((cd ^ rsw) * 8)];
                f16x8 wl = *(const f16x8*)&Wl[rb + ((cd ^ rsw) * 8)];
                acc[et] = __builtin_amdgcn_mfma_f32_32x32x16_f16(wh, xq[ks], acc[et], 0, 0, 0);
                acc[et] = __builtin_amdgcn_mfma_f32_32x32x16_f16(wl, xq[ks], acc[et], 0, 0, 0);
            }
        }

        const float sc = 0.125f * 1.44269504088896340736f;
        const size_t qbase = ((size_t)(b * kS + tok)) * kE + h * kD;
#pragma unroll
        for (int et = 0; et < 2; ++et)
#pragma unroll
            for (int m = 0; m < 4; ++m) {
                const int e0 = 32 * et + 8 * m + 4 * hi;
                f16x4 hv, lv;
#pragma unroll
                for (int j = 0; j < 4; ++j) {
                    _Float16 a, c;
                    split_f16(acc[et][4 * m + j] * sc, a, c);
                    hv[j] = a; lv[j] = c;
                }
                *(f16x4*)(Qhf + qbase + e0) = hv;
                *(f16x4*)(Qlf + qbase + e0) = lv;
            }
    }
}

// ---------------------------------------------------------------------------
// Output-projection GEMM (f16 MFMA): C f32 = A @ Bw^T + bias.
// BM=128, BN=64, BK=64, dbuf -> 512 blocks, 48KB LDS (3 resident/CU).
// ---------------------------------------------------------------------------
__global__ __launch_bounds__(256) void gemm_out(
    const _Float16* __restrict__ A, const _Float16* __restrict__ Bw,
    const float* __restrict__ bias, float* __restrict__ C,
    int M, int N, int K)
{
    __shared__ _Float16 Ab[2][128 * 64];
    __shared__ _Float16 Bb[2][64 * 64];

    const int tid = threadIdx.x;
    const int w = tid >> 6, l = tid & 63;
    const int g = l >> 4, lm = l & 15;
    const int wm = w >> 1, wn = w & 1;
    const int bm = blockIdx.y * 128, bn = blockIdx.x * 64;
    const int srow = 8 * w + (l >> 3);
    const int cp = l & 7;

    f32x4 acc[4][2];
#pragma unroll
    for (int i = 0; i < 4; ++i)
#pragma unroll
        for (int j = 0; j < 2; ++j) acc[i][j] = (f32x4){0.f, 0.f, 0.f, 0.f};

    auto stage = [&](int buf, int k0) {
#pragma unroll
        for (int j = 0; j < 4; ++j) {
            const int r = 32 * j + srow;
            const int c = cp ^ (r & 7);
            gload_lds16(A + (size_t)(bm + r) * K + k0 + c * 8, &Ab[buf][j * 2048 + w * 512]);
        }
#pragma unroll
        for (int j = 0; j < 2; ++j) {
            const int r = 32 * j + srow;
            const int c = cp ^ (r & 7);
            gload_lds16(Bw + (size_t)(bn + r) * K + k0 + c * 8, &Bb[buf][j * 2048 + w * 512]);
        }
    };

    stage(0, 0);
    __syncthreads();
    int cur = 0;
    const int NT = K / 64;
    for (int t = 0; t < NT; ++t) {
        if (t + 1 < NT) stage(cur ^ 1, 64 * (t + 1));
        f16x8 a[4][2], bf[2][2];
#pragma unroll
        for (int i = 0; i < 4; ++i) {
            const int rA = wm * 64 + i * 16 + lm;
#pragma unroll
            for (int ks = 0; ks < 2; ++ks)
                a[i][ks] = *(const f16x8*)&Ab[cur][rA * 64 + (((4 * ks + g) ^ (rA & 7)) * 8)];
        }
#pragma unroll
        for (int i = 0; i < 2; ++i) {
            const int rB = wn * 32 + i * 16 + lm;
#pragma unroll
            for (int ks = 0; ks < 2; ++ks)
                bf[i][ks] = *(const f16x8*)&Bb[cur][rB * 64 + (((4 * ks + g) ^ (rB & 7)) * 8)];
        }
        __builtin_amdgcn_s_setprio(1);
#pragma unroll
        for (int ks = 0; ks < 2; ++ks)
#pragma unroll
            for (int mi = 0; mi < 4; ++mi)
#pragma unroll
                for (int ni = 0; ni < 2; ++ni)
                    acc[mi][ni] = __builtin_amdgcn_mfma_f32_16x16x32_f16(
                        a[mi][ks], bf[ni][ks], acc[mi][ni], 0, 0, 0);
        __builtin_amdgcn_s_setprio(0);
        __syncthreads();
        cur ^= 1;
    }

    float bv2[2];
#pragma unroll
    for (int ni = 0; ni < 2; ++ni) bv2[ni] = bias[bn + wn * 32 + ni * 16 + lm];
#pragma unroll
    for (int mi = 0; mi < 4; ++mi) {
        const int row0 = bm + wm * 64 + mi * 16 + g * 4;
#pragma unroll
        for (int r = 0; r < 4; ++r) {
            float* crow = C + (size_t)(row0 + r) * N;
#pragma unroll
            for (int ni = 0; ni < 2; ++ni)
                crow[bn + wn * 32 + ni * 16 + lm] = acc[mi][ni][r] + bv2[ni];
        }
    }
}

// ---------------------------------------------------------------------------
// MFMA flash attention (r26 structure): tile skip + diagonal-first rotation +
// two tiles per barrier (4 LDS buffers).
// ---------------------------------------------------------------------------
__global__ __launch_bounds__(256, 2) void flash_attn_mfma(
    const _Float16* __restrict__ Qhf, const _Float16* __restrict__ Qlf,
    const _Float16* __restrict__ xf, const _Float16* __restrict__ VtG,
    _Float16* __restrict__ AO)
{
    __shared__ _Float16 Kf[4][64 * 64];
    __shared__ _Float16 Vts[4][64 * 64];

    const int tid = threadIdx.x;
    const int l = tid & 63;
    const int w = tid >> 6;
    const int hi = l >> 5;
    const int lq = l & 31;

    // XCD-chunked remap: 512 blocks, 8 XCDs, 64 works/XCD.
    const int s = blockIdx.x + 16 * blockIdx.y + 256 * blockIdx.z;
    const int wk = (s & 7) * 64 + (s >> 3);
    const int q0 = (wk & 15) * 128;
    const int h = (wk >> 4) & 15;
    const int b = wk >> 8;
    const int tdiag = (wk & 15) * 2;   // first k-tile containing this q-block's diagonal

    f16x8 qh[4], ql[4];
    {
        const size_t qoff = ((size_t)(b * kS + q0 + 32 * w + lq)) * kE + h * kD + 8 * hi;
#pragma unroll
        for (int ks = 0; ks < 4; ++ks) {
            qh[ks] = *(const f16x8*)(Qhf + qoff + 16 * ks);
            ql[ks] = *(const f16x8*)(Qlf + qoff + 16 * ks);
        }
    }
    f16x8 ones;
#pragma unroll
    for (int j = 0; j < 8; ++j) ones[j] = (_Float16)1.0f;

    f32x16 oacc[2], lacc;
#pragma unroll
    for (int r = 0; r < 16; ++r) { oacc[0][r] = 0.f; oacc[1][r] = 0.f; lacc[r] = 0.f; }
    float mrun = -INFINITY;

    const int srow = 8 * w + (l >> 3);
    const int cpos = l & 7;
    const size_t vthead = ((size_t)(b * kH + h) * kD) * kS;
    const size_t xbase = (size_t)(b * kS) * kE + h * kD;

    // Hoisted lane-constant LDS element offsets.
    int koff[2][4];
    int vo[2][2][2];
#pragma unroll
    for (int kt = 0; kt < 2; ++kt) {
        const int key = 32 * kt + lq;
        const int kr = key * 64, ksw = key & 7;
#pragma unroll
        for (int ks = 0; ks < 4; ++ks)
            koff[kt][ks] = kr + (((2 * ks + hi) ^ ksw) * 8);
    }
#pragma unroll
    for (int dt = 0; dt < 2; ++dt) {
        const int d = 32 * dt + lq;
        const int dr = d * 64, dsw = d & 7;
#pragma unroll
        for (int kt = 0; kt < 2; ++kt) {
            vo[dt][kt][0] = dr + (((4 * kt + hi) ^ dsw) * 8);
            vo[dt][kt][1] = dr + (((4 * kt + 2 + hi) ^ dsw) * 8);
        }
    }

    auto stage = [&](int buf, int k0) {
#pragma unroll
        for (int j = 0; j < 2; ++j) {
            const int r = 32 * j + srow;
            const int c = cpos ^ (r & 7);
            gload_lds16(xf + xbase + (size_t)(k0 + r) * kE + c * 8, &Kf[buf][j * 2048 + w * 512]);
            gload_lds16(VtG + vthead + (size_t)r * kS + k0 + c * 8, &Vts[buf][j * 2048 + w * 512]);
        }
    };

    auto tile_body = [&](int curb) {
        f32x16 sacc[2];
#pragma unroll
        for (int r = 0; r < 16; ++r) { sacc[0][r] = 0.f; sacc[1][r] = 0.f; }
        __builtin_amdgcn_s_setprio(1);
#pragma unroll
        for (int ks = 0; ks < 4; ++ks)
#pragma unroll
            for (int kt = 0; kt < 2; ++kt) {
                f16x8 kf = *(const f16x8*)&Kf[curb][koff[kt][ks]];
                sacc[kt] = __builtin_amdgcn_mfma_f32_32x32x16_f16(kf, qh[ks], sacc[kt], 0, 0, 0);
                sacc[kt] = __builtin_amdgcn_mfma_f32_32x32x16_f16(kf, ql[ks], sacc[kt], 0, 0, 0);
            }
        __builtin_amdgcn_s_setprio(0);

        float m0 = max3f(max3f(sacc[0][0], sacc[0][1], sacc[0][2]),
                         max3f(sacc[0][3], sacc[0][4], sacc[0][5]),
                         max3f(sacc[0][6], sacc[0][7], sacc[0][8]));
        float m1 = max3f(max3f(sacc[0][9], sacc[0][10], sacc[0][11]),
                         max3f(sacc[0][12], sacc[0][13], sacc[0][14]),
                         sacc[0][15]);
        float m2 = max3f(max3f(sacc[1][0], sacc[1][1], sacc[1][2]),
                         max3f(sacc[1][3], sacc[1][4], sacc[1][5]),
                         max3f(sacc[1][6], sacc[1][7], sacc[1][8]));
        float m3 = max3f(max3f(sacc[1][9], sacc[1][10], sacc[1][11]),
                         max3f(sacc[1][12], sacc[1][13], sacc[1][14]),
                         sacc[1][15]);
        float tmax = fmaxf(fmaxf(m0, m1), fmaxf(m2, m3));
        tmax = fmaxf(tmax, partner32_f(tmax, hi));

        if (!__any(tmax > mrun - 20.0f)) return;

        if (__any(tmax > mrun + 14.0f)) {
            const float mnew = fmaxf(mrun, tmax);
            const float alpha = exp2f(mrun - mnew);
            oacc[0] *= alpha;
            oacc[1] *= alpha;
            lacc *= alpha;
            mrun = mnew;
        }

#pragma unroll
        for (int kt = 0; kt < 2; ++kt) {
            unsigned wds[8], pw[8];
#pragma unroll
            for (int i = 0; i < 8; ++i) {
                const float p0 = exp2f(sacc[kt][2 * i] - mrun);
                const float p1 = exp2f(sacc[kt][2 * i + 1] - mrun);
                wds[i] = pack_f16(p0, p1);
            }
#pragma unroll
            for (int i = 0; i < 8; ++i) pw[i] = partner32(wds[i], hi);
            u32x4 f0 = hi ? (u32x4){pw[2], pw[3], wds[2], wds[3]}
                          : (u32x4){wds[0], wds[1], pw[0], pw[1]};
            u32x4 f1 = hi ? (u32x4){pw[6], pw[7], wds[6], wds[7]}
                          : (u32x4){wds[4], wds[5], pw[4], pw[5]};
            f16x8 pf0 = __builtin_bit_cast(f16x8, f0);
            f16x8 pf1 = __builtin_bit_cast(f16x8, f1);
            __builtin_amdgcn_s_setprio(1);
            lacc = __builtin_amdgcn_mfma_f32_32x32x16_f16(ones, pf0, lacc, 0, 0, 0);
            lacc = __builtin_amdgcn_mfma_f32_32x32x16_f16(ones, pf1, lacc, 0, 0, 0);
#pragma unroll
            for (int dt = 0; dt < 2; ++dt) {
                f16x8 v0 = *(const f16x8*)&Vts[curb][vo[dt][kt][0]];
                f16x8 v1 = *(const f16x8*)&Vts[curb][vo[dt][kt][1]];
                oacc[dt] = __builtin_amdgcn_mfma_f32_32x32x16_f16(v0, pf0, oacc[dt], 0, 0, 0);
                oacc[dt] = __builtin_amdgcn_mfma_f32_32x32x16_f16(v1, pf1, oacc[dt], 0, 0, 0);
            }
            __builtin_amdgcn_s_setprio(0);
        }
    };

    // Rotated tile order: start at the diagonal k-tiles.
    auto kof = [&](int i) { return ((tdiag + i) & 31) * 64; };

    stage(0, kof(0));
    stage(1, kof(1));
    for (int t = 0; t < 32; t += 2) {
        __syncthreads();                 // buffers t&3, (t+1)&3 staged & drained
        if (t + 2 < 32) stage((t + 2) & 3, kof(t + 2));
        if (t + 3 < 32) stage((t + 3) & 3, kof(t + 3));
        tile_body(t & 3);
        tile_body((t + 1) & 3);
    }

    const float inv = 1.0f / lacc[0];
    const size_t obase = ((size_t)(b * kS + q0 + 32 * w + lq)) * kE + h * kD;
#pragma unroll
    for (int dt = 0; dt < 2; ++dt)
#pragma unroll
        for (int rr = 0; rr < 4; ++rr) {
            const int d0 = 32 * dt + 8 * rr + 4 * hi;
            f16x4 pk;
#pragma unroll
            for (int j = 0; j < 4; ++j) pk[j] = (_Float16)(oacc[dt][4 * rr + j] * inv);
            *(f16x4*)(AO + obase + d0) = pk;
        }
}

// ---------------------------------------------------------------------------
extern "C" void kernel_launch(void* const* d_in, const int* in_sizes, int n_in,
                              void* d_out, int out_size, void* d_ws, size_t ws_size,
                              hipStream_t stream) {
    (void)in_sizes; (void)n_in; (void)out_size; (void)ws_size;
    const float* x      = (const float*)d_in[0];
    const float* params = (const float*)d_in[1];
    const float* Wv     = (const float*)d_in[2];
    const float* bv     = (const float*)d_in[3];
    const float* Wo     = (const float*)d_in[4];
    const float* bo     = (const float*)d_in[5];
    float* out = (float*)d_out;

    const size_t NE = (size_t)kB * kS * kE;   // 4194304
    const size_t NW = (size_t)kE * kE;        // 1048576
    const size_t NQ = (size_t)kH * kD * kD;   // 65536

    char* ws = (char*)d_ws;
    size_t off = 0;
    _Float16* wqkh = (_Float16*)(ws + off); off += NQ * 2;
    _Float16* wqkl = (_Float16*)(ws + off); off += NQ * 2;
    _Float16* xf   = (_Float16*)(ws + off); off += NE * 2;
    _Float16* wvf  = (_Float16*)(ws + off); off += NW * 2;
    _Float16* wof  = (_Float16*)(ws + off); off += NW * 2;
    _Float16* Qhf  = (_Float16*)(ws + off); off += NE * 2;
    _Float16* Qlf  = (_Float16*)(ws + off); off += NE * 2;
    _Float16* VtG  = (_Float16*)(ws + off); off += NE * 2;
    _Float16* AO   = (_Float16*)(ws + off); off += NE * 2;

    setup_kernel<<<6160, 256, 0, stream>>>(Wv, Wo, x, params, wvf, wof, xf, wqkh, wqkl);
    mid_kernel<<<1024, 256, 0, stream>>>(xf, wvf, bv, VtG, wqkh, wqkl, Qhf, Qlf);
    flash_attn_mfma<<<dim3(kS / 128, kH, kB), 256, 0, stream>>>(Qhf, Qlf, xf, VtG, AO);
    gemm_out<<<dim3(kE / 64, (kB * kS) / 128), 256, 0, stream>>>(
        AO, wof, bo, out, kB * kS, kE, kE);
}

// Round 29
// 116.269 us; speedup vs baseline: 1.0652x; 1.0652x over previous
//
#include <hip/hip_runtime.h>
#include <math.h>

// Problem constants
static constexpr int kB = 2;
static constexpr int kS = 2048;
static constexpr int kE = 1024;
static constexpr int kH = 16;
static constexpr int kD = 64;
static constexpr int kTRIL = 2080; // 64*65/2

typedef __attribute__((ext_vector_type(8))) _Float16 f16x8;
typedef __attribute__((ext_vector_type(4))) _Float16 f16x4;
typedef __attribute__((ext_vector_type(2))) __fp16 fp16x2;
typedef __attribute__((ext_vector_type(4))) float f32x4;
typedef __attribute__((ext_vector_type(16))) float f32x16;
typedef __attribute__((ext_vector_type(4))) unsigned int u32x4;
typedef __attribute__((ext_vector_type(2))) unsigned int u32x2;

// Split f32 into f16 hi (RNE) + f16 lo (residual).
__device__ __forceinline__ void split_f16(float f, _Float16& hi, _Float16& lo) {
    hi = (_Float16)f;
    lo = (_Float16)(f - (float)hi);
}

// Async global->LDS 16B copy. LDS dest is wave-uniform (HW adds lane*16).
__device__ __forceinline__ void gload_lds16(const void* g, void* l) {
    __builtin_amdgcn_global_load_lds(
        (const __attribute__((address_space(1))) unsigned int*)g,
        (__attribute__((address_space(3))) unsigned int*)l, 16, 0, 0);
}

// Packed f32x2 -> f16x2 (v_cvt_pkrtz_f16_f32, single VALU op).
__device__ __forceinline__ unsigned pack_f16(float a, float b) {
    fp16x2 p = __builtin_amdgcn_cvt_pkrtz(a, b);
    return __builtin_bit_cast(unsigned, p);
}

// x[lane^32] via v_permlane32_swap (VALU pipe, modeled builtin).
__device__ __forceinline__ unsigned partner32(unsigned x, int hi) {
    u32x2 r = __builtin_amdgcn_permlane32_swap(x, x, false, false);
    return hi ? r[0] : r[1];
}
__device__ __forceinline__ float partner32_f(float x, int hi) {
    return __builtin_bit_cast(float, partner32(__builtin_bit_cast(unsigned, x), hi));
}

__device__ __forceinline__ float max3f(float a, float b, float c) {
    return fmaxf(fmaxf(a, b), c);   // clang fuses to v_max3_f32
}

// ---------------------------------------------------------------------------
// Fused setup:
//   blocks [0,1024)      : cast Wv -> f16
//   blocks [1024,2048)   : cast Wo -> f16
//   blocks [2048,6144)   : cast x -> f16
//   blocks [6144,6160)   : build Wqk[h] = L_h @ L_h^T, split f16 hi/lo
// ---------------------------------------------------------------------------
__global__ __launch_bounds__(256) void setup_kernel(
    const float* __restrict__ Wv, const float* __restrict__ Wo,
    const float* __restrict__ x, const float* __restrict__ params,
    _Float16* __restrict__ wvf, _Float16* __restrict__ wof,
    _Float16* __restrict__ xf,
    _Float16* __restrict__ wqkh, _Float16* __restrict__ wqkl)
{
    const int bid = blockIdx.x;
    if (bid < 2048) {
        const int half = bid >> 10;
        const int i = (bid & 1023) * 256 + threadIdx.x;
        const float* src = half ? Wo : Wv;
        _Float16* dst = half ? wof : wvf;
        const float4 v = ((const float4*)src)[i];
        f16x4 o = {(_Float16)v.x, (_Float16)v.y, (_Float16)v.z, (_Float16)v.w};
        ((f16x4*)dst)[i] = o;
        return;
    }
    if (bid < 6144) {
        const int i = (bid - 2048) * 256 + threadIdx.x;
        const float4 v = ((const float4*)x)[i];
        f16x4 o = {(_Float16)v.x, (_Float16)v.y, (_Float16)v.z, (_Float16)v.w};
        ((f16x4*)xf)[i] = o;
        return;
    }
    // build_wqk for head h (symmetric), emit f16 hi/lo split
    __shared__ float p[kTRIL];
    const int h = bid - 6144;
    for (int i = threadIdx.x; i < kTRIL; i += 256) p[i] = params[h * kTRIL + i];
    __syncthreads();
    for (int idx = threadIdx.x; idx < kD * kD; idx += 256) {
        const int i = idx >> 6;
        const int j = idx & 63;
        const int m = i < j ? i : j;
        const float* pi = p + (i * (i + 1)) / 2;
        const float* pj = p + (j * (j + 1)) / 2;
        float s = 0.f;
        for (int k = 0; k <= m; ++k) s += pi[k] * pj[k];
        _Float16 a, b;
        split_f16(s, a, b);
        wqkh[h * kD * kD + idx] = a;
        wqkl[h * kD * kD + idx] = b;
    }
}

// ---------------------------------------------------------------------------
// Fused middle stage:
//   blocks [0,256)    : V-projection GEMM (f16 MFMA, 128x128) -> VtG f16
//   blocks [256,768)  : Q-projection via MFMA, per (b,h,128-token group).
// ---------------------------------------------------------------------------
__global__ __launch_bounds__(256) void mid_kernel(
    const _Float16* __restrict__ xf, const _Float16* __restrict__ wvf,
    const float* __restrict__ bv, _Float16* __restrict__ VtG,
    const _Float16* __restrict__ wqkh, const _Float16* __restrict__ wqkl,
    _Float16* __restrict__ Qhf, _Float16* __restrict__ Qlf)
{
    __shared__ char arena[65536];
    const int tid = threadIdx.x;
    const int w = tid >> 6, l = tid & 63;
    const int srow = 8 * w + (l >> 3);
    const int cpos = l & 7;

    if (blockIdx.x < 256) {
        _Float16 (*Ab)[128 * 64] = (_Float16 (*)[128 * 64])arena;
        _Float16 (*Bb)[128 * 64] = (_Float16 (*)[128 * 64])(arena + 32768);
        const int K_ = kE;
        const int g = l >> 4, lm = l & 15;
        const int wm = w >> 1, wn = w & 1;
        const int bm = (blockIdx.x >> 3) * 128, bn = (blockIdx.x & 7) * 128;

        f32x4 acc[4][4];
#pragma unroll
        for (int i = 0; i < 4; ++i)
#pragma unroll
            for (int j = 0; j < 4; ++j) acc[i][j] = (f32x4){0.f, 0.f, 0.f, 0.f};

        auto stage = [&](int buf, int k0) {
#pragma unroll
            for (int j = 0; j < 4; ++j) {
                const int r = 32 * j + srow;
                const int c = cpos ^ (r & 7);
                gload_lds16(xf + (size_t)(bm + r) * K_ + k0 + c * 8, &Ab[buf][j * 2048 + w * 512]);
                gload_lds16(wvf + (size_t)(bn + r) * K_ + k0 + c * 8, &Bb[buf][j * 2048 + w * 512]);
            }
        };

        stage(0, 0);
        __syncthreads();
        int cur = 0;
        const int NT = K_ / 64;
        for (int t = 0; t < NT; ++t) {
            if (t + 1 < NT) stage(cur ^ 1, 64 * (t + 1));
            f16x8 a[4][2], bf[4][2];
#pragma unroll
            for (int i = 0; i < 4; ++i) {
                const int rA = wm * 64 + i * 16 + lm;
                const int rB = wn * 64 + i * 16 + lm;
#pragma unroll
                for (int ks = 0; ks < 2; ++ks) {
                    a[i][ks]  = *(const f16x8*)&Ab[cur][rA * 64 + (((4 * ks + g) ^ (rA & 7)) * 8)];
                    bf[i][ks] = *(const f16x8*)&Bb[cur][rB * 64 + (((4 * ks + g) ^ (rB & 7)) * 8)];
                }
            }
            __builtin_amdgcn_s_setprio(1);
#pragma unroll
            for (int ks = 0; ks < 2; ++ks)
#pragma unroll
                for (int mi = 0; mi < 4; ++mi)
#pragma unroll
                    for (int ni = 0; ni < 4; ++ni)
                        acc[mi][ni] = __builtin_amdgcn_mfma_f32_16x16x32_f16(
                            a[mi][ks], bf[ni][ks], acc[mi][ni], 0, 0, 0);
            __builtin_amdgcn_s_setprio(0);
            __syncthreads();
            cur ^= 1;
        }

#pragma unroll
        for (int ni = 0; ni < 4; ++ni) {
            const int col = bn + wn * 64 + ni * 16 + lm;
            const float bb = bv[col];
            const int hh = col >> 6, dd = col & 63;
#pragma unroll
            for (int mi = 0; mi < 4; ++mi) {
                const int tok = bm + wm * 64 + mi * 16 + g * 4;
                const int b = tok >> 11, s0 = tok & 2047;
                f16x4 pk;
#pragma unroll
                for (int r = 0; r < 4; ++r) pk[r] = (_Float16)(acc[mi][ni][r] + bb);
                *(f16x4*)(VtG + ((size_t)(b * kH + hh) * kD + dd) * kS + s0) = pk;
            }
        }
    } else {
        // ---------------- Q projection via MFMA ----------------
        _Float16* Wh = (_Float16*)arena;                 // [64][64] swizzled
        _Float16* Wl = (_Float16*)(arena + 8192);
        const int wk = blockIdx.x - 256;
        const int b = wk >> 8;
        const int h = (wk >> 4) & 15;
        const int tg = wk & 15;
        const int hi = l >> 5;
        const int lq = l & 31;

#pragma unroll
        for (int j = 0; j < 2; ++j) {
            const int r = 32 * j + srow;
            const int c = cpos ^ (r & 7);
            gload_lds16(wqkh + (size_t)(h * kD + r) * kD + c * 8, &Wh[j * 2048 + w * 512]);
            gload_lds16(wqkl + (size_t)(h * kD + r) * kD + c * 8, &Wl[j * 2048 + w * 512]);
        }

        const int tok = tg * 128 + 32 * w + lq;
        f16x8 xq[4];
        {
            const size_t xoff = ((size_t)(b * kS + tok)) * kE + h * kD + 8 * hi;
#pragma unroll
            for (int ks = 0; ks < 4; ++ks)
                xq[ks] = *(const f16x8*)(xf + xoff + 16 * ks);
        }
        f32x16 acc[2];
#pragma unroll
        for (int r = 0; r < 16; ++r) { acc[0][r] = 0.f; acc[1][r] = 0.f; }
        __syncthreads();

#pragma unroll
        for (int et = 0; et < 2; ++et) {
            const int r = 32 * et + lq;
            const int rb = r * 64;
            const int rsw = r & 7;
#pragma unroll
            for (int ks = 0; ks < 4; ++ks) {
                const int cd = 2 * ks + hi;
                f16x8 wh = *(const f16x8*)&Wh[rb + ((cd ^ rsw) * 8)];
                f16x8 wl = *(const f16x8*)&Wl[rb + ((cd ^ rsw) * 8)];
                acc[et] = __builtin_amdgcn_mfma_f32_32x32x16_f16(wh, xq[ks], acc[et], 0, 0, 0);
                acc[et] = __builtin_amdgcn_mfma_f32_32x32x16_f16(wl, xq[ks], acc[et], 0, 0, 0);
            }
        }

        const float sc = 0.125f * 1.44269504088896340736f;
        const size_t qbase = ((size_t)(b * kS + tok)) * kE + h * kD;
#pragma unroll
        for (int et = 0; et < 2; ++et)
#pragma unroll
            for (int m = 0; m < 4; ++m) {
                const int e0 = 32 * et + 8 * m + 4 * hi;
                f16x4 hv, lv;
#pragma unroll
                for (int j = 0; j < 4; ++j) {
                    _Float16 a, c;
                    split_f16(acc[et][4 * m + j] * sc, a, c);
                    hv[j] = a; lv[j] = c;
                }
                *(f16x4*)(Qhf + qbase + e0) = hv;
                *(f16x4*)(Qlf + qbase + e0) = lv;
            }
    }
}

// ---------------------------------------------------------------------------
// Output-projection GEMM (f16 MFMA): C f32 = A @ Bw^T + bias. 128x128, BK=64.
// ---------------------------------------------------------------------------
__global__ __launch_bounds__(256) void gemm_out(
    const _Float16* __restrict__ A, const _Float16* __restrict__ Bw,
    const float* __restrict__ bias, float* __restrict__ C,
    int M, int N, int K)
{
    __shared__ _Float16 Ab[2][128 * 64];
    __shared__ _Float16 Bb[2][128 * 64];

    const int tid = threadIdx.x;
    const int w = tid >> 6, l = tid & 63;
    const int g = l >> 4, lm = l & 15;
    const int wm = w >> 1, wn = w & 1;
    const int bm = blockIdx.y * 128, bn = blockIdx.x * 128;
    const int srow = 8 * w + (l >> 3);
    const int cp = l & 7;

    f32x4 acc[4][4];
#pragma unroll
    for (int i = 0; i < 4; ++i)
#pragma unroll
        for (int j = 0; j < 4; ++j) acc[i][j] = (f32x4){0.f, 0.f, 0.f, 0.f};

    auto stage = [&](int buf, int k0) {
#pragma unroll
        for (int j = 0; j < 4; ++j) {
            const int r = 32 * j + srow;
            const int c = cp ^ (r & 7);
            gload_lds16(A + (size_t)(bm + r) * K + k0 + c * 8, &Ab[buf][j * 2048 + w * 512]);
            gload_lds16(Bw + (size_t)(bn + r) * K + k0 + c * 8, &Bb[buf][j * 2048 + w * 512]);
        }
    };

    stage(0, 0);
    __syncthreads();
    int cur = 0;
    const int NT = K / 64;
    for (int t = 0; t < NT; ++t) {
        if (t + 1 < NT) stage(cur ^ 1, 64 * (t + 1));
        f16x8 a[4][2], bf[4][2];
#pragma unroll
        for (int i = 0; i < 4; ++i) {
            const int rA = wm * 64 + i * 16 + lm;
            const int rB = wn * 64 + i * 16 + lm;
#pragma unroll
            for (int ks = 0; ks < 2; ++ks) {
                a[i][ks]  = *(const f16x8*)&Ab[cur][rA * 64 + (((4 * ks + g) ^ (rA & 7)) * 8)];
                bf[i][ks] = *(const f16x8*)&Bb[cur][rB * 64 + (((4 * ks + g) ^ (rB & 7)) * 8)];
            }
        }
        __builtin_amdgcn_s_setprio(1);
#pragma unroll
        for (int ks = 0; ks < 2; ++ks)
#pragma unroll
            for (int mi = 0; mi < 4; ++mi)
#pragma unroll
                for (int ni = 0; ni < 4; ++ni)
                    acc[mi][ni] = __builtin_amdgcn_mfma_f32_16x16x32_f16(
                        a[mi][ks], bf[ni][ks], acc[mi][ni], 0, 0, 0);
        __builtin_amdgcn_s_setprio(0);
        __syncthreads();
        cur ^= 1;
    }

    float bv4[4];
#pragma unroll
    for (int ni = 0; ni < 4; ++ni) bv4[ni] = bias[bn + wn * 64 + ni * 16 + lm];
#pragma unroll
    for (int mi = 0; mi < 4; ++mi) {
        const int row0 = bm + wm * 64 + mi * 16 + g * 4;
#pragma unroll
        for (int r = 0; r < 4; ++r) {
            float* crow = C + (size_t)(row0 + r) * N;
#pragma unroll
            for (int ni = 0; ni < 4; ++ni)
                crow[bn + wn * 64 + ni * 16 + lm] = acc[mi][ni][r] + bv4[ni];
        }
    }
}

// ---------------------------------------------------------------------------
// MFMA flash attention (best config): tile skip + diagonal-first rotation +
// two tiles per barrier (4 LDS buffers).
// ---------------------------------------------------------------------------
__global__ __launch_bounds__(256, 2) void flash_attn_mfma(
    const _Float16* __restrict__ Qhf, const _Float16* __restrict__ Qlf,
    const _Float16* __restrict__ xf, const _Float16* __restrict__ VtG,
    _Float16* __restrict__ AO)
{
    __shared__ _Float16 Kf[4][64 * 64];
    __shared__ _Float16 Vts[4][64 * 64];

    const int tid = threadIdx.x;
    const int l = tid & 63;
    const int w = tid >> 6;
    const int hi = l >> 5;
    const int lq = l & 31;

    // XCD-chunked remap: 512 blocks, 8 XCDs, 64 works/XCD.
    const int s = blockIdx.x + 16 * blockIdx.y + 256 * blockIdx.z;
    const int wk = (s & 7) * 64 + (s >> 3);
    const int q0 = (wk & 15) * 128;
    const int h = (wk >> 4) & 15;
    const int b = wk >> 8;
    const int tdiag = (wk & 15) * 2;   // first k-tile containing this q-block's diagonal

    f16x8 qh[4], ql[4];
    {
        const size_t qoff = ((size_t)(b * kS + q0 + 32 * w + lq)) * kE + h * kD + 8 * hi;
#pragma unroll
        for (int ks = 0; ks < 4; ++ks) {
            qh[ks] = *(const f16x8*)(Qhf + qoff + 16 * ks);
            ql[ks] = *(const f16x8*)(Qlf + qoff + 16 * ks);
        }
    }
    f16x8 ones;
#pragma unroll
    for (int j = 0; j < 8; ++j) ones[j] = (_Float16)1.0f;

    f32x16 oacc[2], lacc;
#pragma unroll
    for (int r = 0; r < 16; ++r) { oacc[0][r] = 0.f; oacc[1][r] = 0.f; lacc[r] = 0.f; }
    float mrun = -INFINITY;

    const int srow = 8 * w + (l >> 3);
    const int cpos = l & 7;
    const size_t vthead = ((size_t)(b * kH + h) * kD) * kS;
    const size_t xbase = (size_t)(b * kS) * kE + h * kD;

    // Hoisted lane-constant LDS element offsets.
    int koff[2][4];
    int vo[2][2][2];
#pragma unroll
    for (int kt = 0; kt < 2; ++kt) {
        const int key = 32 * kt + lq;
        const int kr = key * 64, ksw = key & 7;
#pragma unroll
        for (int ks = 0; ks < 4; ++ks)
            koff[kt][ks] = kr + (((2 * ks + hi) ^ ksw) * 8);
    }
#pragma unroll
    for (int dt = 0; dt < 2; ++dt) {
        const int d = 32 * dt + lq;
        const int dr = d * 64, dsw = d & 7;
#pragma unroll
        for (int kt = 0; kt < 2; ++kt) {
            vo[dt][kt][0] = dr + (((4 * kt + hi) ^ dsw) * 8);
            vo[dt][kt][1] = dr + (((4 * kt + 2 + hi) ^ dsw) * 8);
        }
    }

    auto stage = [&](int buf, int k0) {
#pragma unroll
        for (int j = 0; j < 2; ++j) {
            const int r = 32 * j + srow;
            const int c = cpos ^ (r & 7);
            gload_lds16(xf + xbase + (size_t)(k0 + r) * kE + c * 8, &Kf[buf][j * 2048 + w * 512]);
            gload_lds16(VtG + vthead + (size_t)r * kS + k0 + c * 8, &Vts[buf][j * 2048 + w * 512]);
        }
    };

    auto tile_body = [&](int curb) {
        f32x16 sacc[2];
#pragma unroll
        for (int r = 0; r < 16; ++r) { sacc[0][r] = 0.f; sacc[1][r] = 0.f; }
        __builtin_amdgcn_s_setprio(1);
#pragma unroll
        for (int ks = 0; ks < 4; ++ks)
#pragma unroll
            for (int kt = 0; kt < 2; ++kt) {
                f16x8 kf = *(const f16x8*)&Kf[curb][koff[kt][ks]];
                sacc[kt] = __builtin_amdgcn_mfma_f32_32x32x16_f16(kf, qh[ks], sacc[kt], 0, 0, 0);
                sacc[kt] = __builtin_amdgcn_mfma_f32_32x32x16_f16(kf, ql[ks], sacc[kt], 0, 0, 0);
            }
        __builtin_amdgcn_s_setprio(0);

        float m0 = max3f(max3f(sacc[0][0], sacc[0][1], sacc[0][2]),
                         max3f(sacc[0][3], sacc[0][4], sacc[0][5]),
                         max3f(sacc[0][6], sacc[0][7], sacc[0][8]));
        float m1 = max3f(max3f(sacc[0][9], sacc[0][10], sacc[0][11]),
                         max3f(sacc[0][12], sacc[0][13], sacc[0][14]),
                         sacc[0][15]);
        float m2 = max3f(max3f(sacc[1][0], sacc[1][1], sacc[1][2]),
                         max3f(sacc[1][3], sacc[1][4], sacc[1][5]),
                         max3f(sacc[1][6], sacc[1][7], sacc[1][8]));
        float m3 = max3f(max3f(sacc[1][9], sacc[1][10], sacc[1][11]),
                         max3f(sacc[1][12], sacc[1][13], sacc[1][14]),
                         sacc[1][15]);
        float tmax = fmaxf(fmaxf(m0, m1), fmaxf(m2, m3));
        tmax = fmaxf(tmax, partner32_f(tmax, hi));

        if (!__any(tmax > mrun - 20.0f)) return;

        if (__any(tmax > mrun + 14.0f)) {
            const float mnew = fmaxf(mrun, tmax);
            const float alpha = exp2f(mrun - mnew);
            oacc[0] *= alpha;
            oacc[1] *= alpha;
            lacc *= alpha;
            mrun = mnew;
        }

#pragma unroll
        for (int kt = 0; kt < 2; ++kt) {
            unsigned wds[8], pw[8];
#pragma unroll
            for (int i = 0; i < 8; ++i) {
                const float p0 = exp2f(sacc[kt][2 * i] - mrun);
                const float p1 = exp2f(sacc[kt][2 * i + 1] - mrun);
                wds[i] = pack_f16(p0, p1);
            }
#pragma unroll
            for (int i = 0; i < 8; ++i) pw[i] = partner32(wds[i], hi);
            u32x4 f0 = hi ? (u32x4){pw[2], pw[3], wds[2], wds[3]}
                          : (u32x4){wds[0], wds[1], pw[0], pw[1]};
            u32x4 f1 = hi ? (u32x4){pw[6], pw[7], wds[6], wds[7]}
                          : (u32x4){wds[4], wds[5], pw[4], pw[5]};
            f16x8 pf0 = __builtin_bit_cast(f16x8, f0);
            f16x8 pf1 = __builtin_bit_cast(f16x8, f1);
            __builtin_amdgcn_s_setprio(1);
            lacc = __builtin_amdgcn_mfma_f32_32x32x16_f16(ones, pf0, lacc, 0, 0, 0);
            lacc = __builtin_amdgcn_mfma_f32_32x32x16_f16(ones, pf1, lacc, 0, 0, 0);
#pragma unroll
            for (int dt = 0; dt < 2; ++dt) {
                f16x8 v0 = *(const f16x8*)&Vts[curb][vo[dt][kt][0]];
                f16x8 v1 = *(const f16x8*)&Vts[curb][vo[dt][kt][1]];
                oacc[dt] = __builtin_amdgcn_mfma_f32_32x32x16_f16(v0, pf0, oacc[dt], 0, 0, 0);
                oacc[dt] = __builtin_amdgcn_mfma_f32_32x32x16_f16(v1, pf1, oacc[dt], 0, 0, 0);
            }
            __builtin_amdgcn_s_setprio(0);
        }
    };

    // Rotated tile order: start at the diagonal k-tiles.
    auto kof = [&](int i) { return ((tdiag + i) & 31) * 64; };

    stage(0, kof(0));
    stage(1, kof(1));
    for (int t = 0; t < 32; t += 2) {
        __syncthreads();                 // buffers t&3, (t+1)&3 staged & drained
        if (t + 2 < 32) stage((t + 2) & 3, kof(t + 2));
        if (t + 3 < 32) stage((t + 3) & 3, kof(t + 3));
        tile_body(t & 3);
        tile_body((t + 1) & 3);
    }

    const float inv = 1.0f / lacc[0];
    const size_t obase = ((size_t)(b * kS + q0 + 32 * w + lq)) * kE + h * kD;
#pragma unroll
    for (int dt = 0; dt < 2; ++dt)
#pragma unroll
        for (int rr = 0; rr < 4; ++rr) {
            const int d0 = 32 * dt + 8 * rr + 4 * hi;
            f16x4 pk;
#pragma unroll
            for (int j = 0; j < 4; ++j) pk[j] = (_Float16)(oacc[dt][4 * rr + j] * inv);
            *(f16x4*)(AO + obase + d0) = pk;
        }
}

// ---------------------------------------------------------------------------
extern "C" void kernel_launch(void* const* d_in, const int* in_sizes, int n_in,
                              void* d_out, int out_size, void* d_ws, size_t ws_size,
                              hipStream_t stream) {
    (void)in_sizes; (void)n_in; (void)out_size; (void)ws_size;
    const float* x      = (const float*)d_in[0];
    const float* params = (const float*)d_in[1];
    const float* Wv     = (const float*)d_in[2];
    const float* bv     = (const float*)d_in[3];
    const float* Wo     = (const float*)d_in[4];
    const float* bo     = (const float*)d_in[5];
    float* out = (float*)d_out;

    const size_t NE = (size_t)kB * kS * kE;   // 4194304
    const size_t NW = (size_t)kE * kE;        // 1048576
    const size_t NQ = (size_t)kH * kD * kD;   // 65536

    char* ws = (char*)d_ws;
    size_t off = 0;
    _Float16* wqkh = (_Float16*)(ws + off); off += NQ * 2;
    _Float16* wqkl = (_Float16*)(ws + off); off += NQ * 2;
    _Float16* xf   = (_Float16*)(ws + off); off += NE * 2;
    _Float16* wvf  = (_Float16*)(ws + off); off += NW * 2;
    _Float16* wof  = (_Float16*)(ws + off); off += NW * 2;
    _Float16* Qhf  = (_Float16*)(ws + off); off += NE * 2;
    _Float16* Qlf  = (_Float16*)(ws + off); off += NE * 2;
    _Float16* VtG  = (_Float16*)(ws + off); off += NE * 2;
    _Float16* AO   = (_Float16*)(ws + off); off += NE * 2;

    setup_kernel<<<6160, 256, 0, stream>>>(Wv, Wo, x, params, wvf, wof, xf, wqkh, wqkl);
    mid_kernel<<<768, 256, 0, stream>>>(xf, wvf, bv, VtG, wqkh, wqkl, Qhf, Qlf);
    flash_attn_mfma<<<dim3(kS / 128, kH, kB), 256, 0, stream>>>(Qhf, Qlf, xf, VtG, AO);
    gemm_out<<<dim3(kE / 128, (kB * kS) / 128), 256, 0, stream>>>(
        AO, wof, bo, out, kB * kS, kE, kE);
}